// Round 4
// baseline (144.918 us; speedup 1.0000x reference)
//
#include <hip/hip_runtime.h>
#include <math.h>

#define B_ 2
#define T_ 8
#define N_ 2048
#define F_ 64
#define TI 16
#define JC 64
#define JCP 72
#define NJH 4                 // 4-way j split
#define NCH (N_ / NJH / JC)   // 8 chunks per block
#define LOG2E 1.44269504088896f

typedef __attribute__((ext_vector_type(8))) short short8;
typedef __attribute__((ext_vector_type(4))) float f32x4;

__device__ __forceinline__ unsigned short f2bf(float x) {
  unsigned u = __float_as_uint(x);
  u += 0x7FFFu + ((u >> 16) & 1u);
  return (unsigned short)(u >> 16);
}

__device__ __forceinline__ unsigned cvt_pk_bf16(float lo, float hi) {
  unsigned r;
  asm("v_cvt_pk_bf16_f32 %0, %1, %2" : "=v"(r) : "v"(lo), "v"(hi));
  return r;
}

__device__ __forceinline__ float bf_lo(unsigned u) { return __uint_as_float(u << 16); }
__device__ __forceinline__ float bf_hi(unsigned u) { return __uint_as_float(u & 0xFFFF0000u); }

// ---------------- prep: Wh = h@W (fp32), WhT bf16 [bt][f][j], Wh1/Wh2 (pre-scaled by log2e)
__global__ __launch_bounds__(256) void prep_kernel(
    const float* __restrict__ h, const float* __restrict__ W,
    const float* __restrict__ a, unsigned short* __restrict__ WhT,
    float* __restrict__ Wh1, float* __restrict__ Wh2) {
  __shared__ float Ws[64][64];
  __shared__ float hs[64][64];
  __shared__ float Whs[64][65];
  const int tid = threadIdx.x;
  const int row0 = blockIdx.x * 64;   // row in flattened [B*T*N]
  const int bt = row0 >> 11;
  const int j0 = row0 & 2047;
  for (int i = tid; i < 4096; i += 256) Ws[i >> 6][i & 63] = W[i];
  for (int i = tid; i < 4096; i += 256) hs[i >> 6][i & 63] = h[(size_t)row0 * 64 + i];
  __syncthreads();
  const int f = tid & 63;
  const int rq = tid >> 6;
  float acc[16];
#pragma unroll
  for (int m = 0; m < 16; ++m) acc[m] = 0.f;
#pragma unroll 4
  for (int k = 0; k < 64; ++k) {
    const float wvv = Ws[k][f];
#pragma unroll
    for (int m = 0; m < 16; ++m) acc[m] = fmaf(hs[rq * 16 + m][k], wvv, acc[m]);
  }
#pragma unroll
  for (int m = 0; m < 16; ++m) Whs[rq * 16 + m][f] = acc[m];
  __syncthreads();
  {
    const int r = tid >> 2, q = tid & 3;
    float s1 = 0.f, s2 = 0.f;
#pragma unroll
    for (int k = 0; k < 16; ++k) {
      const float v = Whs[r][q * 16 + k];
      s1 = fmaf(v, a[q * 16 + k], s1);
      s2 = fmaf(v, a[64 + q * 16 + k], s2);
    }
    s1 += __shfl_xor(s1, 1); s1 += __shfl_xor(s1, 2);
    s2 += __shfl_xor(s2, 1); s2 += __shfl_xor(s2, 2);
    if (q == 0) {
      // pre-scale by log2(e): LeakyReLU is positively homogeneous, so
      // exp(LRelu(w1+w2)) == exp2(LRelu(log2e*w1 + log2e*w2))
      Wh1[(size_t)bt * N_ + j0 + r] = s1 * LOG2E;
      Wh2[(size_t)bt * N_ + j0 + r] = s2 * LOG2E;
    }
  }
  {
    const int ff = tid & 63, cp = tid >> 6;
#pragma unroll
    for (int cc = 0; cc < 2; ++cc) {
      const int c = cp * 2 + cc;
      short8 v;
#pragma unroll
      for (int k = 0; k < 8; ++k) v[k] = (short)f2bf(Whs[c * 8 + k][ff]);
      *(short8*)(WhT + ((size_t)bt * 64 + ff) * N_ + j0 + c * 8) = v;
    }
  }
}

// ---------------- main: softmax-over-T attention + MFMA PV -> bf16 partials
// grid 1024: jh = bx&3, itile = (bx>>2)&127, b = bx>>9
// partial jh0/jh1 -> lo/hi bf16 of out words; jh2/jh3 -> lo/hi of part words
__global__ __launch_bounds__(512, 8) void gat_mfma(
    const unsigned short* __restrict__ WhT, const float* __restrict__ Wh1,
    const float* __restrict__ Wh2, const int* __restrict__ adj,
    unsigned* __restrict__ outw, unsigned* __restrict__ partw) {
  __shared__ unsigned short atts[2][T_][TI][JCP];  // 36864 B
  __shared__ float wh2s[2][T_][JC];                // 4096 B  (total 40960 = 4 blocks/CU)
  const int tid = threadIdx.x;
  const int jh = blockIdx.x & 3;
  const int i0 = ((blockIdx.x >> 2) & 127) * TI;
  const int b = blockIdx.x >> 9;
  const int jbase = jh * (N_ / NJH);

  const int wv = tid >> 6;        // wave id == t
  const int lane = tid & 63;
  const int col = lane & 15;
  const int kg = lane >> 4;

  const int sii = tid >> 5;          // softmax i-row 0..15
  const int sjj = (tid & 31) * 2;    // softmax j-cols (sjj, sjj+1)
  const int st = tid >> 6, sj = tid & 63;  // wh2 staging assignment

  const unsigned short* wtb = WhT + (size_t)(b * T_ + wv) * F_ * N_;
  const float* wh2b = Wh2 + (size_t)b * T_ * N_;
  const int* adjrow = adj + (size_t)(i0 + sii) * N_ + jbase;

  // Wh1 row for this thread's softmax i-row (broadcast L2 loads, once)
  float w1r[T_];
#pragma unroll
  for (int t = 0; t < T_; ++t) w1r[t] = Wh1[(size_t)(b * T_ + t) * N_ + i0 + sii];

  f32x4 acc[4];
#pragma unroll
  for (int nt = 0; nt < 4; ++nt) acc[nt] = {0.f, 0.f, 0.f, 0.f};

  // prologue: stage wh2 chunk 0, prefetch adj chunk 0
  wh2s[0][st][sj] = wh2b[(size_t)st * N_ + jbase + sj];
  int2 ad = *(const int2*)(adjrow + sjj);
  __syncthreads();

  for (int c = 0; c < NCH; ++c) {
    const int j0 = jbase + c * JC;
    const int buf = c & 1;
    // --- issue B-fragment global loads early
    short8 breg[4][2];
#pragma unroll
    for (int nt = 0; nt < 4; ++nt)
#pragma unroll
      for (int ks = 0; ks < 2; ++ks)
        breg[nt][ks] = *(const short8*)(wtb + (size_t)(nt * 16 + col) * N_ +
                                        j0 + ks * 32 + kg * 8);
    // --- stage next chunk's Wh2 (safe: buf^1 readers all passed barrier(c-1))
    if (c + 1 < NCH)
      wh2s[buf ^ 1][st][sj] = wh2b[(size_t)st * N_ + j0 + JC + sj];
    // --- prefetch next chunk's adj
    int2 adn = ad;
    if (c + 1 < NCH) adn = *(const int2*)(adjrow + (c + 1) * JC + sjj);

    // --- softmax over T for columns (sjj, sjj+1), row sii; no max pass needed
    {
      float e0[T_], e1[T_];
      float s0 = 0.f, s1 = 0.f;
#pragma unroll
      for (int t = 0; t < T_; ++t) {
        const float2 w2 = *(const float2*)(&wh2s[buf][t][sjj]);
        float x0 = w1r[t] + w2.x;
        float x1 = w1r[t] + w2.y;
        x0 = fmaxf(x0, 0.2f * x0);   // LeakyReLU (alpha<1, scale-commuting)
        x1 = fmaxf(x1, 0.2f * x1);
        e0[t] = __builtin_amdgcn_exp2f(x0);
        e1[t] = __builtin_amdgcn_exp2f(x1);
        s0 += e0[t];
        s1 += e1[t];
      }
      // adj==0 -> all-NEG_INF column -> softmax over t uniform 1/8:
      const float r0 = ad.x > 0 ? __builtin_amdgcn_rcpf(s0) : 0.f;
      const float r1 = ad.y > 0 ? __builtin_amdgcn_rcpf(s1) : 0.f;
      const float d0 = ad.x > 0 ? 0.f : 0.125f;
      const float d1 = ad.y > 0 ? 0.f : 0.125f;
#pragma unroll
      for (int t = 0; t < T_; ++t) {
        const float a0 = fmaf(e0[t], r0, d0);
        const float a1 = fmaf(e1[t], r1, d1);
        *(unsigned*)&atts[buf][t][sii][sjj] = cvt_pk_bf16(a0, a1);
      }
    }
    ad = adn;
    __syncthreads();
    // --- MFMA: A = att[16i x 64j], B = WhT[64f x 64j] both bf16
    const unsigned short* ab = &atts[buf][wv][col][kg * 8];
    const short8 a0 = *(const short8*)ab;
    const short8 a1 = *(const short8*)(ab + 32);
#pragma unroll
    for (int nt = 0; nt < 4; ++nt) {
      acc[nt] = __builtin_amdgcn_mfma_f32_16x16x32_bf16(a0, breg[nt][0], acc[nt], 0, 0, 0);
      acc[nt] = __builtin_amdgcn_mfma_f32_16x16x32_bf16(a1, breg[nt][1], acc[nt], 0, 0, 0);
    }
  }

  // ---- epilogue: bf16 partial into lo/hi half of the u32 word
  unsigned* dstw = (jh & 2) ? partw : outw;
  unsigned short* dsth = (unsigned short*)dstw + (jh & 1);
  const size_t base = ((size_t)(b * T_ + wv) * N_ + i0) * F_;
#pragma unroll
  for (int nt = 0; nt < 4; ++nt) {
#pragma unroll
    for (int r = 0; r < 4; ++r) {
      const int row = kg * 4 + r;
      const size_t idx = base + (size_t)row * F_ + nt * 16 + col;
      dsth[idx * 2] = f2bf(acc[nt][r]);
    }
  }
}

// ---------------- combine 4 bf16 partials + ELU
__global__ __launch_bounds__(256) void combine_elu(
    float* __restrict__ out, const unsigned* __restrict__ partw) {
  const size_t e0 = ((size_t)blockIdx.x * 256 + threadIdx.x) * 4;
  unsigned* outw = (unsigned*)out;
  uint4 o = *(const uint4*)(outw + e0);
  const uint4 p = *(const uint4*)(partw + e0);
  float r[4];
  r[0] = bf_lo(o.x) + bf_hi(o.x) + bf_lo(p.x) + bf_hi(p.x);
  r[1] = bf_lo(o.y) + bf_hi(o.y) + bf_lo(p.y) + bf_hi(p.y);
  r[2] = bf_lo(o.z) + bf_hi(o.z) + bf_lo(p.z) + bf_hi(p.z);
  r[3] = bf_lo(o.w) + bf_hi(o.w) + bf_lo(p.w) + bf_hi(p.w);
  f32x4 res;
#pragma unroll
  for (int k = 0; k < 4; ++k) res[k] = r[k] > 0.f ? r[k] : expm1f(r[k]);
  *(f32x4*)(out + e0) = res;
}

extern "C" void kernel_launch(void* const* d_in, const int* in_sizes, int n_in,
                              void* d_out, int out_size, void* d_ws, size_t ws_size,
                              hipStream_t stream) {
  const float* h   = (const float*)d_in[0];
  const float* W   = (const float*)d_in[1];
  const float* a   = (const float*)d_in[2];
  const int*   adj = (const int*)d_in[3];
  float* out = (float*)d_out;

  const size_t whtBytes = (size_t)B_ * T_ * F_ * N_ * 2;    // 4MB
  unsigned short* WhT = (unsigned short*)d_ws;
  float* Wh1  = (float*)((char*)d_ws + whtBytes);
  float* Wh2  = Wh1 + (size_t)B_ * T_ * N_;
  unsigned* partw = (unsigned*)(Wh2 + (size_t)B_ * T_ * N_);  // 8MB (bf16 pairs)

  hipLaunchKernelGGL(prep_kernel, dim3(B_ * T_ * N_ / 64), dim3(256), 0, stream,
                     h, W, a, WhT, Wh1, Wh2);
  hipLaunchKernelGGL(gat_mfma, dim3(B_ * 128 * NJH), dim3(512), 0, stream,
                     WhT, Wh1, Wh2, adj, (unsigned*)out, partw);
  hipLaunchKernelGGL(combine_elu, dim3(B_ * T_ * N_ * F_ / (256 * 4)), dim3(256),
                     0, stream, out, partw);
}